// Round 1
// baseline (683.194 us; speedup 1.0000x reference)
//
#include <hip/hip_runtime.h>

// DeformableGCN: 3x mean-smoothing + 2x attention-weighted GCN conv.
// Strategy: CSR-by-dst once, node-level transforms (z = h@W, a1/a2 attention
// dots), wave-per-dst-node gather for all segment sums. No float atomics.

__global__ void count_deg_kernel(const int* __restrict__ dst, int* __restrict__ deg, int E) {
    int e = blockIdx.x * blockDim.x + threadIdx.x;
    if (e < E) atomicAdd(&deg[dst[e]], 1);
}

// Single-block scan over N degrees -> exclusive row_ptr, plus cursor copy.
__global__ void scan_kernel(const int* __restrict__ deg, int* __restrict__ row_ptr,
                            int* __restrict__ cursor, int N) {
    __shared__ int sums[1024];
    int t = threadIdx.x;
    int T = blockDim.x;
    int C = (N + T - 1) / T;
    int start = t * C;
    int end = start + C; if (end > N) end = N;
    int s = 0;
    for (int i = start; i < end; ++i) s += deg[i];
    sums[t] = s;
    __syncthreads();
    for (int off = 1; off < T; off <<= 1) {
        int v = 0;
        if (t >= off) v = sums[t - off];
        __syncthreads();
        sums[t] += v;
        __syncthreads();
    }
    int base = sums[t] - s;   // exclusive prefix of this thread's chunk
    for (int i = start; i < end; ++i) {
        row_ptr[i] = base;
        cursor[i] = base;
        base += deg[i];
    }
    if (t == T - 1) row_ptr[N] = sums[t];
}

__global__ void scatter_kernel(const int* __restrict__ src, const int* __restrict__ dst,
                               int* __restrict__ cursor, int* __restrict__ src_idx, int E) {
    int e = blockIdx.x * blockDim.x + threadIdx.x;
    if (e < E) {
        int slot = atomicAdd(&cursor[dst[e]], 1);
        src_idx[slot] = src[e];
    }
}

__global__ void xs_init_kernel(const float* __restrict__ x, float* __restrict__ xs, int total4) {
    int i = blockIdx.x * blockDim.x + threadIdx.x;
    if (i < total4) ((float4*)xs)[i] = ((const float4*)x)[i];
}

// One wave per dst node; lane = feature (D=64). h_out = mean of incoming h[src];
// xs += h_out (smoothing accumulator fused in).
__global__ void agg_mean_kernel(const float* __restrict__ h, const int* __restrict__ row_ptr,
                                const int* __restrict__ src_idx,
                                float* __restrict__ h_out, float* __restrict__ xs, int N) {
    int wid = (blockIdx.x * blockDim.x + threadIdx.x) >> 6;
    int lane = threadIdx.x & 63;
    if (wid >= N) return;
    int beg = row_ptr[wid], end = row_ptr[wid + 1];
    float v = 0.f;
    for (int e = beg; e < end; ++e) {
        int s = src_idx[e];
        v += h[(size_t)s * 64 + lane];
    }
    int d = end - beg;
    if (d > 0) v /= (float)d;
    h_out[(size_t)wid * 64 + lane] = v;
    xs[(size_t)wid * 64 + lane] += v;
}

// Per-node transform for conv1: z1 = (xs*0.25) @ W_lin1 (64x64),
// a1 = (xs*0.25)·W_att1[0:64], a2 = (xs*0.25)·W_att1[64:128].
__global__ void xform1_kernel(const float* __restrict__ xs, const float* __restrict__ W_lin1,
                              const float* __restrict__ W_att1,
                              float* __restrict__ z1, float* __restrict__ a1, float* __restrict__ a2,
                              int N) {
    __shared__ float row[4][64];
    int wib = threadIdx.x >> 6;
    int lane = threadIdx.x & 63;
    int n = blockIdx.x * 4 + wib;
    int nc = n < N ? n : N - 1;
    float xv = xs[(size_t)nc * 64 + lane] * 0.25f;  // fold /(STEPS+1)
    row[wib][lane] = xv;
    __syncthreads();
    float p1 = xv * W_att1[lane];
    float p2 = xv * W_att1[64 + lane];
    for (int off = 32; off > 0; off >>= 1) {
        p1 += __shfl_down(p1, off, 64);
        p2 += __shfl_down(p2, off, 64);
    }
    float acc = 0.f;
    #pragma unroll
    for (int k = 0; k < 64; ++k) acc += row[wib][k] * W_lin1[k * 64 + lane];
    if (n < N) {
        z1[(size_t)n * 64 + lane] = acc;
        if (lane == 0) { a1[n] = p1; a2[n] = p2; }
    }
}

// Per-node transform for conv2: z2 = h1 @ W_lin2 (64x32), attention dots with W_att2.
__global__ void xform2_kernel(const float* __restrict__ h1, const float* __restrict__ W_lin2,
                              const float* __restrict__ W_att2,
                              float* __restrict__ z2, float* __restrict__ a1, float* __restrict__ a2,
                              int N) {
    __shared__ float row[4][64];
    int wib = threadIdx.x >> 6;
    int lane = threadIdx.x & 63;
    int n = blockIdx.x * 4 + wib;
    int nc = n < N ? n : N - 1;
    float hv = h1[(size_t)nc * 64 + lane];
    row[wib][lane] = hv;
    __syncthreads();
    float p1 = hv * W_att2[lane];
    float p2 = hv * W_att2[64 + lane];
    for (int off = 32; off > 0; off >>= 1) {
        p1 += __shfl_down(p1, off, 64);
        p2 += __shfl_down(p2, off, 64);
    }
    float acc = 0.f;
    if (lane < 32) {
        #pragma unroll
        for (int k = 0; k < 64; ++k) acc += row[wib][k] * W_lin2[k * 32 + lane];
    }
    if (n < N) {
        if (lane < 32) z2[(size_t)n * 32 + lane] = acc;
        if (lane == 0) { a1[n] = p1; a2[n] = p2; }
    }
}

// Conv1 aggregation: one wave per dst node, D=64. feats = sum leaky(a1[s]+a2[n]+b)*z1[s];
// writes relu(feats).
__global__ void agg_conv64_kernel(const float* __restrict__ z, const float* __restrict__ a1,
                                  const float* __restrict__ a2, const float* __restrict__ b_att,
                                  const int* __restrict__ row_ptr, const int* __restrict__ src_idx,
                                  float* __restrict__ outp, int N) {
    int wid = (blockIdx.x * blockDim.x + threadIdx.x) >> 6;
    int lane = threadIdx.x & 63;
    if (wid >= N) return;
    float ad = a2[wid] + b_att[0];
    int beg = row_ptr[wid], end = row_ptr[wid + 1];
    float v = 0.f;
    for (int e = beg; e < end; ++e) {
        int s = src_idx[e];
        float sc = a1[s] + ad;
        sc = sc > 0.f ? sc : 0.01f * sc;   // leaky_relu, slope 0.01
        v += sc * z[(size_t)s * 64 + lane];
    }
    outp[(size_t)wid * 64 + lane] = fmaxf(v, 0.f);   // relu after conv1
}

// Conv2 aggregation: two dst nodes per wave (32 features each), no activation.
__global__ void agg_conv32_kernel(const float* __restrict__ z, const float* __restrict__ a1,
                                  const float* __restrict__ a2, const float* __restrict__ b_att,
                                  const int* __restrict__ row_ptr, const int* __restrict__ src_idx,
                                  float* __restrict__ outp, int N) {
    int wid = (blockIdx.x * blockDim.x + threadIdx.x) >> 6;
    int lane = threadIdx.x & 63;
    int node = wid * 2 + (lane >> 5);
    int lane32 = lane & 31;
    if (node >= N) return;
    float ad = a2[node] + b_att[0];
    int beg = row_ptr[node], end = row_ptr[node + 1];
    float v = 0.f;
    for (int e = beg; e < end; ++e) {
        int s = src_idx[e];
        float sc = a1[s] + ad;
        sc = sc > 0.f ? sc : 0.01f * sc;
        v += sc * z[(size_t)s * 32 + lane32];
    }
    outp[(size_t)node * 32 + lane32] = v;
}

extern "C" void kernel_launch(void* const* d_in, const int* in_sizes, int n_in,
                              void* d_out, int out_size, void* d_ws, size_t ws_size,
                              hipStream_t stream) {
    const float* x      = (const float*)d_in[0];
    const int*   ei     = (const int*)d_in[1];
    const float* W_att1 = (const float*)d_in[2];
    const float* b_att1 = (const float*)d_in[3];
    const float* W_lin1 = (const float*)d_in[4];
    const float* W_att2 = (const float*)d_in[5];
    const float* b_att2 = (const float*)d_in[6];
    const float* W_lin2 = (const float*)d_in[7];
    float* out = (float*)d_out;

    int N = in_sizes[0] / 64;
    int E = in_sizes[1] / 2;
    const int* src = ei;       // edge_index[0]
    const int* dst = ei + E;   // edge_index[1]

    char* ws = (char*)d_ws;
    size_t off = 0;
    auto alloc = [&](size_t bytes) -> void* {
        void* p = ws + off;
        off += (bytes + 255) & ~(size_t)255;
        return p;
    };
    int*   deg     = (int*)alloc((size_t)N * 4);
    int*   row_ptr = (int*)alloc((size_t)(N + 1) * 4);
    int*   cursor  = (int*)alloc((size_t)N * 4);
    int*   src_idx = (int*)alloc((size_t)E * 4);
    float* bufA    = (float*)alloc((size_t)N * 64 * 4);
    float* bufB    = (float*)alloc((size_t)N * 64 * 4);
    float* xs      = (float*)alloc((size_t)N * 64 * 4);
    float* a1      = (float*)alloc((size_t)N * 4);
    float* a2      = (float*)alloc((size_t)N * 4);
    float* a1b     = (float*)alloc((size_t)N * 4);
    float* a2b     = (float*)alloc((size_t)N * 4);
    // Buffer reuse after smoothing: z1 <- bufB, h1 <- bufA, z2 <- xs.
    float* z1 = bufB;
    float* h1 = bufA;
    float* z2 = xs;

    const int tb = 256;
    hipMemsetAsync(deg, 0, (size_t)N * 4, stream);
    count_deg_kernel<<<(E + tb - 1) / tb, tb, 0, stream>>>(dst, deg, E);
    scan_kernel<<<1, 1024, 0, stream>>>(deg, row_ptr, cursor, N);
    scatter_kernel<<<(E + tb - 1) / tb, tb, 0, stream>>>(src, dst, cursor, src_idx, E);

    int total4 = N * 16;  // N*64 floats as float4
    xs_init_kernel<<<(total4 + tb - 1) / tb, tb, 0, stream>>>(x, xs, total4);

    int aggBlocks = (N * 64 + tb - 1) / tb;   // one wave (64 lanes) per node
    agg_mean_kernel<<<aggBlocks, tb, 0, stream>>>(x,    row_ptr, src_idx, bufA, xs, N);
    agg_mean_kernel<<<aggBlocks, tb, 0, stream>>>(bufA, row_ptr, src_idx, bufB, xs, N);
    agg_mean_kernel<<<aggBlocks, tb, 0, stream>>>(bufB, row_ptr, src_idx, bufA, xs, N);

    int xfBlocks = (N + 3) / 4;
    xform1_kernel<<<xfBlocks, 256, 0, stream>>>(xs, W_lin1, W_att1, z1, a1, a2, N);
    agg_conv64_kernel<<<aggBlocks, tb, 0, stream>>>(z1, a1, a2, b_att1, row_ptr, src_idx, h1, N);
    xform2_kernel<<<xfBlocks, 256, 0, stream>>>(h1, W_lin2, W_att2, z2, a1b, a2b, N);

    int waves32 = (N + 1) / 2;  // two nodes per wave
    agg_conv32_kernel<<<(waves32 * 64 + tb - 1) / tb, tb, 0, stream>>>(
        z2, a1b, a2b, b_att2, row_ptr, src_idx, out, N);
}

// Round 2
// 585.929 us; speedup vs baseline: 1.1660x; 1.1660x over previous
//
#include <hip/hip_runtime.h>

// DeformableGCN: 3x mean-smoothing + 2x attention-weighted GCN conv.
// Strategy: CSR-by-dst once, node-level transforms (z = h@W, a1/a2 attention
// dots), wave-per-dst-node gather for all segment sums. No float atomics.
// R1: two-level multi-block scan replaces the 110us single-block scan.

__global__ void count_deg_kernel(const int* __restrict__ dst, int* __restrict__ deg, int E) {
    int e = blockIdx.x * blockDim.x + threadIdx.x;
    if (e < E) atomicAdd(&deg[dst[e]], 1);
}

// --- two-level scan: block reduce -> scan block sums -> block scan + offset ---

__global__ void block_sum_kernel(const int* __restrict__ deg, int* __restrict__ blockSums, int N) {
    __shared__ int sh[256];
    int i = blockIdx.x * 256 + threadIdx.x;
    int v = (i < N) ? deg[i] : 0;
    sh[threadIdx.x] = v;
    __syncthreads();
    for (int off = 128; off > 0; off >>= 1) {
        if (threadIdx.x < off) sh[threadIdx.x] += sh[threadIdx.x + off];
        __syncthreads();
    }
    if (threadIdx.x == 0) blockSums[blockIdx.x] = sh[0];
}

// single block, 1024 threads; B <= 1024. Converts blockSums to exclusive
// offsets in place; writes grand total to row_ptr[N].
__global__ void scan_sums_kernel(int* __restrict__ blockSums, int* __restrict__ row_ptr_N, int B) {
    __shared__ int sh[1024];
    int t = threadIdx.x;
    int v = (t < B) ? blockSums[t] : 0;
    sh[t] = v;
    __syncthreads();
    for (int off = 1; off < 1024; off <<= 1) {
        int u = (t >= off) ? sh[t - off] : 0;
        __syncthreads();
        sh[t] += u;
        __syncthreads();
    }
    if (t < B) blockSums[t] = sh[t] - v;   // exclusive prefix
    if (t == 1023) row_ptr_N[0] = sh[1023]; // total = row_ptr[N]
}

__global__ void write_rowptr_kernel(const int* __restrict__ deg, const int* __restrict__ blockOffs,
                                    int* __restrict__ row_ptr, int* __restrict__ cursor, int N) {
    __shared__ int sh[256];
    int i = blockIdx.x * 256 + threadIdx.x;
    int v = (i < N) ? deg[i] : 0;
    sh[threadIdx.x] = v;
    __syncthreads();
    for (int off = 1; off < 256; off <<= 1) {
        int u = (threadIdx.x >= off) ? sh[threadIdx.x - off] : 0;
        __syncthreads();
        sh[threadIdx.x] += u;
        __syncthreads();
    }
    if (i < N) {
        int excl = blockOffs[blockIdx.x] + sh[threadIdx.x] - v;
        row_ptr[i] = excl;
        cursor[i] = excl;
    }
}

__global__ void scatter_kernel(const int* __restrict__ src, const int* __restrict__ dst,
                               int* __restrict__ cursor, int* __restrict__ src_idx, int E) {
    int e = blockIdx.x * blockDim.x + threadIdx.x;
    if (e < E) {
        int slot = atomicAdd(&cursor[dst[e]], 1);
        src_idx[slot] = src[e];
    }
}

__global__ void xs_init_kernel(const float* __restrict__ x, float* __restrict__ xs, int total4) {
    int i = blockIdx.x * blockDim.x + threadIdx.x;
    if (i < total4) ((float4*)xs)[i] = ((const float4*)x)[i];
}

// One wave per dst node; lane = feature (D=64). h_out = mean of incoming h[src];
// xs += h_out (smoothing accumulator fused in).
__global__ void agg_mean_kernel(const float* __restrict__ h, const int* __restrict__ row_ptr,
                                const int* __restrict__ src_idx,
                                float* __restrict__ h_out, float* __restrict__ xs, int N) {
    int wid = (blockIdx.x * blockDim.x + threadIdx.x) >> 6;
    int lane = threadIdx.x & 63;
    if (wid >= N) return;
    int beg = row_ptr[wid], end = row_ptr[wid + 1];
    float v = 0.f;
    for (int e = beg; e < end; ++e) {
        int s = src_idx[e];
        v += h[(size_t)s * 64 + lane];
    }
    int d = end - beg;
    if (d > 0) v /= (float)d;
    h_out[(size_t)wid * 64 + lane] = v;
    xs[(size_t)wid * 64 + lane] += v;
}

// Per-node transform for conv1: z1 = (xs*0.25) @ W_lin1 (64x64),
// a1 = (xs*0.25)·W_att1[0:64], a2 = (xs*0.25)·W_att1[64:128].
__global__ void xform1_kernel(const float* __restrict__ xs, const float* __restrict__ W_lin1,
                              const float* __restrict__ W_att1,
                              float* __restrict__ z1, float* __restrict__ a1, float* __restrict__ a2,
                              int N) {
    __shared__ float row[4][64];
    int wib = threadIdx.x >> 6;
    int lane = threadIdx.x & 63;
    int n = blockIdx.x * 4 + wib;
    int nc = n < N ? n : N - 1;
    float xv = xs[(size_t)nc * 64 + lane] * 0.25f;  // fold /(STEPS+1)
    row[wib][lane] = xv;
    __syncthreads();
    float p1 = xv * W_att1[lane];
    float p2 = xv * W_att1[64 + lane];
    for (int off = 32; off > 0; off >>= 1) {
        p1 += __shfl_down(p1, off, 64);
        p2 += __shfl_down(p2, off, 64);
    }
    float acc = 0.f;
    #pragma unroll
    for (int k = 0; k < 64; ++k) acc += row[wib][k] * W_lin1[k * 64 + lane];
    if (n < N) {
        z1[(size_t)n * 64 + lane] = acc;
        if (lane == 0) { a1[n] = p1; a2[n] = p2; }
    }
}

// Per-node transform for conv2: z2 = h1 @ W_lin2 (64x32), attention dots with W_att2.
__global__ void xform2_kernel(const float* __restrict__ h1, const float* __restrict__ W_lin2,
                              const float* __restrict__ W_att2,
                              float* __restrict__ z2, float* __restrict__ a1, float* __restrict__ a2,
                              int N) {
    __shared__ float row[4][64];
    int wib = threadIdx.x >> 6;
    int lane = threadIdx.x & 63;
    int n = blockIdx.x * 4 + wib;
    int nc = n < N ? n : N - 1;
    float hv = h1[(size_t)nc * 64 + lane];
    row[wib][lane] = hv;
    __syncthreads();
    float p1 = hv * W_att2[lane];
    float p2 = hv * W_att2[64 + lane];
    for (int off = 32; off > 0; off >>= 1) {
        p1 += __shfl_down(p1, off, 64);
        p2 += __shfl_down(p2, off, 64);
    }
    float acc = 0.f;
    if (lane < 32) {
        #pragma unroll
        for (int k = 0; k < 64; ++k) acc += row[wib][k] * W_lin2[k * 32 + lane];
    }
    if (n < N) {
        if (lane < 32) z2[(size_t)n * 32 + lane] = acc;
        if (lane == 0) { a1[n] = p1; a2[n] = p2; }
    }
}

// Conv1 aggregation: one wave per dst node, D=64. feats = sum leaky(a1[s]+a2[n]+b)*z1[s];
// writes relu(feats).
__global__ void agg_conv64_kernel(const float* __restrict__ z, const float* __restrict__ a1,
                                  const float* __restrict__ a2, const float* __restrict__ b_att,
                                  const int* __restrict__ row_ptr, const int* __restrict__ src_idx,
                                  float* __restrict__ outp, int N) {
    int wid = (blockIdx.x * blockDim.x + threadIdx.x) >> 6;
    int lane = threadIdx.x & 63;
    if (wid >= N) return;
    float ad = a2[wid] + b_att[0];
    int beg = row_ptr[wid], end = row_ptr[wid + 1];
    float v = 0.f;
    for (int e = beg; e < end; ++e) {
        int s = src_idx[e];
        float sc = a1[s] + ad;
        sc = sc > 0.f ? sc : 0.01f * sc;   // leaky_relu, slope 0.01
        v += sc * z[(size_t)s * 64 + lane];
    }
    outp[(size_t)wid * 64 + lane] = fmaxf(v, 0.f);   // relu after conv1
}

// Conv2 aggregation: two dst nodes per wave (32 features each), no activation.
__global__ void agg_conv32_kernel(const float* __restrict__ z, const float* __restrict__ a1,
                                  const float* __restrict__ a2, const float* __restrict__ b_att,
                                  const int* __restrict__ row_ptr, const int* __restrict__ src_idx,
                                  float* __restrict__ outp, int N) {
    int wid = (blockIdx.x * blockDim.x + threadIdx.x) >> 6;
    int lane = threadIdx.x & 63;
    int node = wid * 2 + (lane >> 5);
    int lane32 = lane & 31;
    if (node >= N) return;
    float ad = a2[node] + b_att[0];
    int beg = row_ptr[node], end = row_ptr[node + 1];
    float v = 0.f;
    for (int e = beg; e < end; ++e) {
        int s = src_idx[e];
        float sc = a1[s] + ad;
        sc = sc > 0.f ? sc : 0.01f * sc;
        v += sc * z[(size_t)s * 32 + lane32];
    }
    outp[(size_t)node * 32 + lane32] = v;
}

extern "C" void kernel_launch(void* const* d_in, const int* in_sizes, int n_in,
                              void* d_out, int out_size, void* d_ws, size_t ws_size,
                              hipStream_t stream) {
    const float* x      = (const float*)d_in[0];
    const int*   ei     = (const int*)d_in[1];
    const float* W_att1 = (const float*)d_in[2];
    const float* b_att1 = (const float*)d_in[3];
    const float* W_lin1 = (const float*)d_in[4];
    const float* W_att2 = (const float*)d_in[5];
    const float* b_att2 = (const float*)d_in[6];
    const float* W_lin2 = (const float*)d_in[7];
    float* out = (float*)d_out;

    int N = in_sizes[0] / 64;
    int E = in_sizes[1] / 2;
    const int* src = ei;       // edge_index[0]
    const int* dst = ei + E;   // edge_index[1]

    char* ws = (char*)d_ws;
    size_t off = 0;
    auto alloc = [&](size_t bytes) -> void* {
        void* p = ws + off;
        off += (bytes + 255) & ~(size_t)255;
        return p;
    };
    int*   deg     = (int*)alloc((size_t)N * 4);
    int*   row_ptr = (int*)alloc((size_t)(N + 1) * 4);
    int*   cursor  = (int*)alloc((size_t)N * 4);
    int*   src_idx = (int*)alloc((size_t)E * 4);
    int*   blockSums = (int*)alloc((size_t)1024 * 4);
    float* bufA    = (float*)alloc((size_t)N * 64 * 4);
    float* bufB    = (float*)alloc((size_t)N * 64 * 4);
    float* xs      = (float*)alloc((size_t)N * 64 * 4);
    float* a1      = (float*)alloc((size_t)N * 4);
    float* a2      = (float*)alloc((size_t)N * 4);
    float* a1b     = (float*)alloc((size_t)N * 4);
    float* a2b     = (float*)alloc((size_t)N * 4);
    // Buffer reuse after smoothing: z1 <- bufB, h1 <- bufA, z2 <- xs.
    float* z1 = bufB;
    float* h1 = bufA;
    float* z2 = xs;

    const int tb = 256;
    hipMemsetAsync(deg, 0, (size_t)N * 4, stream);
    count_deg_kernel<<<(E + tb - 1) / tb, tb, 0, stream>>>(dst, deg, E);

    int B = (N + 255) / 256;   // 196 for N=50000; scan_sums handles B<=1024
    block_sum_kernel<<<B, 256, 0, stream>>>(deg, blockSums, N);
    scan_sums_kernel<<<1, 1024, 0, stream>>>(blockSums, row_ptr + N, B);
    write_rowptr_kernel<<<B, 256, 0, stream>>>(deg, blockSums, row_ptr, cursor, N);

    scatter_kernel<<<(E + tb - 1) / tb, tb, 0, stream>>>(src, dst, cursor, src_idx, E);

    int total4 = N * 16;  // N*64 floats as float4
    xs_init_kernel<<<(total4 + tb - 1) / tb, tb, 0, stream>>>(x, xs, total4);

    int aggBlocks = (N * 64 + tb - 1) / tb;   // one wave (64 lanes) per node
    agg_mean_kernel<<<aggBlocks, tb, 0, stream>>>(x,    row_ptr, src_idx, bufA, xs, N);
    agg_mean_kernel<<<aggBlocks, tb, 0, stream>>>(bufA, row_ptr, src_idx, bufB, xs, N);
    agg_mean_kernel<<<aggBlocks, tb, 0, stream>>>(bufB, row_ptr, src_idx, bufA, xs, N);

    int xfBlocks = (N + 3) / 4;
    xform1_kernel<<<xfBlocks, 256, 0, stream>>>(xs, W_lin1, W_att1, z1, a1, a2, N);
    agg_conv64_kernel<<<aggBlocks, tb, 0, stream>>>(z1, a1, a2, b_att1, row_ptr, src_idx, h1, N);
    xform2_kernel<<<xfBlocks, 256, 0, stream>>>(h1, W_lin2, W_att2, z2, a1b, a2b, N);

    int waves32 = (N + 1) / 2;  // two nodes per wave
    agg_conv32_kernel<<<(waves32 * 64 + tb - 1) / tb, tb, 0, stream>>>(
        z2, a1b, a2b, b_att2, row_ptr, src_idx, out, N);
}

// Round 3
// 371.838 us; speedup vs baseline: 1.8373x; 1.5758x over previous
//
#include <hip/hip_runtime.h>

// DeformableGCN: 3x mean-smoothing + 2x attention-weighted GCN conv.
// CSR-by-dst, node-level transforms, wave-per-dst-node gathers.
// R1: two-level scan. R2: 4-edges-per-instruction float4 gathers (16 lanes x
// float4 = one 64-float row), x2 unroll = 8 edges in flight; xs accumulator
// folded into xform1 (h1/h2/h3 kept in separate buffers).

__global__ void count_deg_kernel(const int* __restrict__ dst, int* __restrict__ deg, int E) {
    int e = blockIdx.x * blockDim.x + threadIdx.x;
    if (e < E) atomicAdd(&deg[dst[e]], 1);
}

__global__ void block_sum_kernel(const int* __restrict__ deg, int* __restrict__ blockSums, int N) {
    __shared__ int sh[256];
    int i = blockIdx.x * 256 + threadIdx.x;
    int v = (i < N) ? deg[i] : 0;
    sh[threadIdx.x] = v;
    __syncthreads();
    for (int off = 128; off > 0; off >>= 1) {
        if (threadIdx.x < off) sh[threadIdx.x] += sh[threadIdx.x + off];
        __syncthreads();
    }
    if (threadIdx.x == 0) blockSums[blockIdx.x] = sh[0];
}

__global__ void scan_sums_kernel(int* __restrict__ blockSums, int* __restrict__ row_ptr_N, int B) {
    __shared__ int sh[1024];
    int t = threadIdx.x;
    int v = (t < B) ? blockSums[t] : 0;
    sh[t] = v;
    __syncthreads();
    for (int off = 1; off < 1024; off <<= 1) {
        int u = (t >= off) ? sh[t - off] : 0;
        __syncthreads();
        sh[t] += u;
        __syncthreads();
    }
    if (t < B) blockSums[t] = sh[t] - v;
    if (t == 1023) row_ptr_N[0] = sh[1023];
}

__global__ void write_rowptr_kernel(const int* __restrict__ deg, const int* __restrict__ blockOffs,
                                    int* __restrict__ row_ptr, int* __restrict__ cursor, int N) {
    __shared__ int sh[256];
    int i = blockIdx.x * 256 + threadIdx.x;
    int v = (i < N) ? deg[i] : 0;
    sh[threadIdx.x] = v;
    __syncthreads();
    for (int off = 1; off < 256; off <<= 1) {
        int u = (threadIdx.x >= off) ? sh[threadIdx.x - off] : 0;
        __syncthreads();
        sh[threadIdx.x] += u;
        __syncthreads();
    }
    if (i < N) {
        int excl = blockOffs[blockIdx.x] + sh[threadIdx.x] - v;
        row_ptr[i] = excl;
        cursor[i] = excl;
    }
}

__global__ void scatter_kernel(const int* __restrict__ src, const int* __restrict__ dst,
                               int* __restrict__ cursor, int* __restrict__ src_idx, int E) {
    int e = blockIdx.x * blockDim.x + threadIdx.x;
    if (e < E) {
        int slot = atomicAdd(&cursor[dst[e]], 1);
        src_idx[slot] = src[e];
    }
}

// Mean aggregation, one wave per dst node. 4 lane-groups x 16 lanes; each
// group handles 2 edges per iteration (8 edges in flight).
__global__ void agg_mean_kernel(const float* __restrict__ h, const int* __restrict__ row_ptr,
                                const int* __restrict__ src_idx,
                                float* __restrict__ h_out, int N) {
    int wid = (blockIdx.x * blockDim.x + threadIdx.x) >> 6;
    int lane = threadIdx.x & 63;
    if (wid >= N) return;
    int beg = row_ptr[wid], end = row_ptr[wid + 1];
    int j = lane >> 4;     // edge slot 0..3
    int f = lane & 15;     // float4 block within the 64-float row
    float4 acc0 = make_float4(0.f, 0.f, 0.f, 0.f);
    float4 acc1 = make_float4(0.f, 0.f, 0.f, 0.f);
    for (int e = beg + 2 * j; e < end; e += 8) {
        int s0 = src_idx[e];
        float4 v0 = *((const float4*)(h + (size_t)s0 * 64) + f);
        acc0.x += v0.x; acc0.y += v0.y; acc0.z += v0.z; acc0.w += v0.w;
        if (e + 1 < end) {
            int s1 = src_idx[e + 1];
            float4 v1 = *((const float4*)(h + (size_t)s1 * 64) + f);
            acc1.x += v1.x; acc1.y += v1.y; acc1.z += v1.z; acc1.w += v1.w;
        }
    }
    acc0.x += acc1.x; acc0.y += acc1.y; acc0.z += acc1.z; acc0.w += acc1.w;
    acc0.x += __shfl_down(acc0.x, 32, 64); acc0.y += __shfl_down(acc0.y, 32, 64);
    acc0.z += __shfl_down(acc0.z, 32, 64); acc0.w += __shfl_down(acc0.w, 32, 64);
    acc0.x += __shfl_down(acc0.x, 16, 64); acc0.y += __shfl_down(acc0.y, 16, 64);
    acc0.z += __shfl_down(acc0.z, 16, 64); acc0.w += __shfl_down(acc0.w, 16, 64);
    if (lane < 16) {
        int d = end - beg;
        float inv = d > 0 ? 1.f / (float)d : 0.f;
        float4 o; o.x = acc0.x * inv; o.y = acc0.y * inv; o.z = acc0.z * inv; o.w = acc0.w * inv;
        *((float4*)(h_out + (size_t)wid * 64) + lane) = o;
    }
}

// Conv1 transform: xs = (x+h1+h2+h3)/4 folded in. z1 = xs@W_lin1, a1/a2 dots.
__global__ void xform1_kernel(const float* __restrict__ x, const float* __restrict__ hA,
                              const float* __restrict__ hB, const float* __restrict__ hC,
                              const float* __restrict__ W_lin1, const float* __restrict__ W_att1,
                              float* __restrict__ z1, float* __restrict__ a1, float* __restrict__ a2,
                              int N) {
    __shared__ float row[4][64];
    int wib = threadIdx.x >> 6;
    int lane = threadIdx.x & 63;
    int n = blockIdx.x * 4 + wib;
    int nc = n < N ? n : N - 1;
    size_t idx = (size_t)nc * 64 + lane;
    float xv = (x[idx] + hA[idx] + hB[idx] + hC[idx]) * 0.25f;
    row[wib][lane] = xv;
    __syncthreads();
    float p1 = xv * W_att1[lane];
    float p2 = xv * W_att1[64 + lane];
    for (int off = 32; off > 0; off >>= 1) {
        p1 += __shfl_down(p1, off, 64);
        p2 += __shfl_down(p2, off, 64);
    }
    float acc = 0.f;
    #pragma unroll
    for (int k = 0; k < 64; ++k) acc += row[wib][k] * W_lin1[k * 64 + lane];
    if (n < N) {
        z1[(size_t)n * 64 + lane] = acc;
        if (lane == 0) { a1[n] = p1; a2[n] = p2; }
    }
}

__global__ void xform2_kernel(const float* __restrict__ h1, const float* __restrict__ W_lin2,
                              const float* __restrict__ W_att2,
                              float* __restrict__ z2, float* __restrict__ a1, float* __restrict__ a2,
                              int N) {
    __shared__ float row[4][64];
    int wib = threadIdx.x >> 6;
    int lane = threadIdx.x & 63;
    int n = blockIdx.x * 4 + wib;
    int nc = n < N ? n : N - 1;
    float hv = h1[(size_t)nc * 64 + lane];
    row[wib][lane] = hv;
    __syncthreads();
    float p1 = hv * W_att2[lane];
    float p2 = hv * W_att2[64 + lane];
    for (int off = 32; off > 0; off >>= 1) {
        p1 += __shfl_down(p1, off, 64);
        p2 += __shfl_down(p2, off, 64);
    }
    float acc = 0.f;
    if (lane < 32) {
        #pragma unroll
        for (int k = 0; k < 64; ++k) acc += row[wib][k] * W_lin2[k * 32 + lane];
    }
    if (n < N) {
        if (lane < 32) z2[(size_t)n * 32 + lane] = acc;
        if (lane == 0) { a1[n] = p1; a2[n] = p2; }
    }
}

// Conv1 aggregation (D=64): 4 lane-groups x 16 lanes, 8 edges in flight,
// per-edge leaky score; writes relu(sum).
__global__ void agg_conv64_kernel(const float* __restrict__ z, const float* __restrict__ a1,
                                  const float* __restrict__ a2, const float* __restrict__ b_att,
                                  const int* __restrict__ row_ptr, const int* __restrict__ src_idx,
                                  float* __restrict__ outp, int N) {
    int wid = (blockIdx.x * blockDim.x + threadIdx.x) >> 6;
    int lane = threadIdx.x & 63;
    if (wid >= N) return;
    float ad = a2[wid] + b_att[0];
    int beg = row_ptr[wid], end = row_ptr[wid + 1];
    int j = lane >> 4;
    int f = lane & 15;
    float4 acc0 = make_float4(0.f, 0.f, 0.f, 0.f);
    float4 acc1 = make_float4(0.f, 0.f, 0.f, 0.f);
    for (int e = beg + 2 * j; e < end; e += 8) {
        int s0 = src_idx[e];
        float sc0 = a1[s0] + ad;
        sc0 = sc0 > 0.f ? sc0 : 0.01f * sc0;
        float4 v0 = *((const float4*)(z + (size_t)s0 * 64) + f);
        acc0.x += sc0 * v0.x; acc0.y += sc0 * v0.y; acc0.z += sc0 * v0.z; acc0.w += sc0 * v0.w;
        if (e + 1 < end) {
            int s1 = src_idx[e + 1];
            float sc1 = a1[s1] + ad;
            sc1 = sc1 > 0.f ? sc1 : 0.01f * sc1;
            float4 v1 = *((const float4*)(z + (size_t)s1 * 64) + f);
            acc1.x += sc1 * v1.x; acc1.y += sc1 * v1.y; acc1.z += sc1 * v1.z; acc1.w += sc1 * v1.w;
        }
    }
    acc0.x += acc1.x; acc0.y += acc1.y; acc0.z += acc1.z; acc0.w += acc1.w;
    acc0.x += __shfl_down(acc0.x, 32, 64); acc0.y += __shfl_down(acc0.y, 32, 64);
    acc0.z += __shfl_down(acc0.z, 32, 64); acc0.w += __shfl_down(acc0.w, 32, 64);
    acc0.x += __shfl_down(acc0.x, 16, 64); acc0.y += __shfl_down(acc0.y, 16, 64);
    acc0.z += __shfl_down(acc0.z, 16, 64); acc0.w += __shfl_down(acc0.w, 16, 64);
    if (lane < 16) {
        float4 o;
        o.x = fmaxf(acc0.x, 0.f); o.y = fmaxf(acc0.y, 0.f);
        o.z = fmaxf(acc0.z, 0.f); o.w = fmaxf(acc0.w, 0.f);
        *((float4*)(outp + (size_t)wid * 64) + lane) = o;
    }
}

// Conv2 aggregation (D=32): 8 lane-groups x 8 lanes, 8 edges in flight.
__global__ void agg_conv32_kernel(const float* __restrict__ z, const float* __restrict__ a1,
                                  const float* __restrict__ a2, const float* __restrict__ b_att,
                                  const int* __restrict__ row_ptr, const int* __restrict__ src_idx,
                                  float* __restrict__ outp, int N) {
    int wid = (blockIdx.x * blockDim.x + threadIdx.x) >> 6;
    int lane = threadIdx.x & 63;
    if (wid >= N) return;
    float ad = a2[wid] + b_att[0];
    int beg = row_ptr[wid], end = row_ptr[wid + 1];
    int j = lane >> 3;   // edge slot 0..7
    int f = lane & 7;    // float4 block within the 32-float row
    float4 acc = make_float4(0.f, 0.f, 0.f, 0.f);
    for (int e = beg + j; e < end; e += 8) {
        int s = src_idx[e];
        float sc = a1[s] + ad;
        sc = sc > 0.f ? sc : 0.01f * sc;
        float4 v = *((const float4*)(z + (size_t)s * 32) + f);
        acc.x += sc * v.x; acc.y += sc * v.y; acc.z += sc * v.z; acc.w += sc * v.w;
    }
    acc.x += __shfl_down(acc.x, 32, 64); acc.y += __shfl_down(acc.y, 32, 64);
    acc.z += __shfl_down(acc.z, 32, 64); acc.w += __shfl_down(acc.w, 32, 64);
    acc.x += __shfl_down(acc.x, 16, 64); acc.y += __shfl_down(acc.y, 16, 64);
    acc.z += __shfl_down(acc.z, 16, 64); acc.w += __shfl_down(acc.w, 16, 64);
    acc.x += __shfl_down(acc.x, 8, 64);  acc.y += __shfl_down(acc.y, 8, 64);
    acc.z += __shfl_down(acc.z, 8, 64);  acc.w += __shfl_down(acc.w, 8, 64);
    if (lane < 8) {
        *((float4*)(outp + (size_t)wid * 32) + lane) = acc;
    }
}

extern "C" void kernel_launch(void* const* d_in, const int* in_sizes, int n_in,
                              void* d_out, int out_size, void* d_ws, size_t ws_size,
                              hipStream_t stream) {
    const float* x      = (const float*)d_in[0];
    const int*   ei     = (const int*)d_in[1];
    const float* W_att1 = (const float*)d_in[2];
    const float* b_att1 = (const float*)d_in[3];
    const float* W_lin1 = (const float*)d_in[4];
    const float* W_att2 = (const float*)d_in[5];
    const float* b_att2 = (const float*)d_in[6];
    const float* W_lin2 = (const float*)d_in[7];
    float* out = (float*)d_out;

    int N = in_sizes[0] / 64;
    int E = in_sizes[1] / 2;
    const int* src = ei;
    const int* dst = ei + E;

    char* ws = (char*)d_ws;
    size_t off = 0;
    auto alloc = [&](size_t bytes) -> void* {
        void* p = ws + off;
        off += (bytes + 255) & ~(size_t)255;
        return p;
    };
    int*   deg       = (int*)alloc((size_t)N * 4);
    int*   row_ptr   = (int*)alloc((size_t)(N + 1) * 4);
    int*   cursor    = (int*)alloc((size_t)N * 4);
    int*   src_idx   = (int*)alloc((size_t)E * 4);
    int*   blockSums = (int*)alloc((size_t)1024 * 4);
    float* bufA      = (float*)alloc((size_t)N * 64 * 4);   // h1
    float* bufB      = (float*)alloc((size_t)N * 64 * 4);   // h2
    float* bufC      = (float*)alloc((size_t)N * 64 * 4);   // h3
    float* bufD      = (float*)alloc((size_t)N * 64 * 4);   // z1 / z2
    float* a1        = (float*)alloc((size_t)N * 4);
    float* a2        = (float*)alloc((size_t)N * 4);
    float* a1b       = (float*)alloc((size_t)N * 4);
    float* a2b       = (float*)alloc((size_t)N * 4);

    const int tb = 256;
    hipMemsetAsync(deg, 0, (size_t)N * 4, stream);
    count_deg_kernel<<<(E + tb - 1) / tb, tb, 0, stream>>>(dst, deg, E);

    int B = (N + 255) / 256;
    block_sum_kernel<<<B, 256, 0, stream>>>(deg, blockSums, N);
    scan_sums_kernel<<<1, 1024, 0, stream>>>(blockSums, row_ptr + N, B);
    write_rowptr_kernel<<<B, 256, 0, stream>>>(deg, blockSums, row_ptr, cursor, N);

    scatter_kernel<<<(E + tb - 1) / tb, tb, 0, stream>>>(src, dst, cursor, src_idx, E);

    int aggBlocks = (N * 64 + tb - 1) / tb;   // one wave per node
    agg_mean_kernel<<<aggBlocks, tb, 0, stream>>>(x,    row_ptr, src_idx, bufA, N);
    agg_mean_kernel<<<aggBlocks, tb, 0, stream>>>(bufA, row_ptr, src_idx, bufB, N);
    agg_mean_kernel<<<aggBlocks, tb, 0, stream>>>(bufB, row_ptr, src_idx, bufC, N);

    int xfBlocks = (N + 3) / 4;
    // z1 -> bufD, then h1(relu feats) -> bufA (h buffers consumed by xform1)
    xform1_kernel<<<xfBlocks, 256, 0, stream>>>(x, bufA, bufB, bufC, W_lin1, W_att1,
                                                bufD, a1, a2, N);
    agg_conv64_kernel<<<aggBlocks, tb, 0, stream>>>(bufD, a1, a2, b_att1, row_ptr, src_idx,
                                                    bufA, N);
    // z2 -> bufB
    xform2_kernel<<<xfBlocks, 256, 0, stream>>>(bufA, W_lin2, W_att2, bufB, a1b, a2b, N);
    agg_conv32_kernel<<<aggBlocks, tb, 0, stream>>>(bufB, a1b, a2b, b_att2, row_ptr, src_idx,
                                                    out, N);
}